// Round 10
// baseline (83.817 us; speedup 1.0000x reference)
//
#include <hip/hip_runtime.h>
#include <math.h>

// DSHW — R15: software-pipelined window scan (W=8, 8 lanes/series).
// R13/R14 established: per-iteration budget = harness ws-poison fill (~41us,
// fixed) + gaps + our kernel (~20-24us). Only the kernel is controllable.
// R13's WIN8 serialized everything behind the spt0 chain (~750 cyc/window).
// True cross-window path is only spt0 -> acc(l7) -> snw(l7) -> bcast -> spt0'.
// This round:
//   * PRE phase: wc/y loads + iw + aur + all 8 aur-bcasts for window k+1
//     issued during window k (DS latency hidden under serial phase)
//   * acc tree: 4x fma(cf,b,cf*b) + 2-level add tree + fma(Pl,spt0,
//     fma(Ql,snp0,v)) — depth 4 (was 9), spt0 enters last
//   * handoff via per-lane snw (already computed for x): 3 bcasts not 4
//   * D' deferred one window (unchanged); loop kept rolled (I-cache, R11)
//   * epilogue: wc staged into freed sY rows then float4-coalesced
// Math formula-identical to R13 (passed); f64 reassoc noise ~1e-16 rel.
// R16: identical resubmission — round 9 failed on container acquisition
// (no timing, no counters). Re-running to test R15's prediction:
// kernel ~20-24 -> ~12-15us, total 83 -> ~75-78us.

#define P1c   24
#define P2c   168
#define NSTEP 512
#define BSc   64
#define NFc   16
#define MAXH  336
#define NSERIES 1024

#define OFF_FC   0
#define OFF_YH   (BSc * MAXH * NFc)
#define OFF_E    (OFF_YH + BSc * NSTEP * NFc)
#define OFF_IC   (OFF_E  + BSc * NSTEP * NFc)
#define OFF_WC   (OFF_IC + BSc * P1c * NFc)
#define OFF_T    (OFF_WC + BSc * P2c * NFc)
#define OFF_S    (OFF_T  + BSc * NFc)

__device__ __forceinline__ double nrcp(double a) {      // 2-NR (init only)
    double x = __builtin_amdgcn_rcp(a);
    x = fma(fma(-a, x, 1.0), x, x);
    x = fma(fma(-a, x, 1.0), x, x);
    return x;
}

__device__ __forceinline__ double nrcp1(double a) {     // 1-NR (PRE)
    double x = __builtin_amdgcn_rcp(a);
    x = fma(fma(-a, x, 1.0), x, x);
    return x;
}

// broadcast lane I (0..7) of each 8-lane group: BitMode and=0x18 or=I xor=0
template<int I>
__device__ __forceinline__ double bcast8(double v) {
    constexpr int pat = (I << 5) | 0x18;
    int lo = __builtin_amdgcn_ds_swizzle(__double2loint(v), pat);
    int hi = __builtin_amdgcn_ds_swizzle(__double2hiint(v), pat);
    return __hiloint2double(hi, lo);
}
// xor-butterfly within 8-lane group: and=0x1f or=0 xor=M
template<int M>
__device__ __forceinline__ double xor8(double v) {
    constexpr int pat = (M << 10) | 0x1f;
    int lo = __builtin_amdgcn_ds_swizzle(__double2loint(v), pat);
    int hi = __builtin_amdgcn_ds_swizzle(__double2hiint(v), pat);
    return __hiloint2double(hi, lo);
}

__global__ __launch_bounds__(128, 1)
void dshw_one(const float* __restrict__ y,
              const float* __restrict__ alphas,
              const float* __restrict__ betas,
              const float* __restrict__ gammas,
              const float* __restrict__ omegas,
              float* __restrict__ out)
{
    __shared__ double sW[P2c][NFc];                   // 21 KiB (wc)
    __shared__ double sIc[P1c][NFc];                  // 3 KiB (final Ic, for fc)
    __shared__ __align__(16) float sY[NSTEP][NFc];    // 32 KiB (y -> yhat -> fc/wc)

    const int tid   = threadIdx.x;
    const int s_loc = tid >> 3;          // 0..15  (feature / series-in-block)
    const int j     = tid & 7;           // lane within series group
    const int bb    = blockIdx.x;        // batch row
    const int f     = s_loc;

    // ---------------- stage y into LDS (fully coalesced) ----------------
    const float4* __restrict__ y4 =
        (const float4*)(y + (size_t)bb * NSTEP * NFc);
    #pragma unroll 4
    for (int i = tid; i < (NSTEP * NFc) / 4; i += 128) {
        float4 v = y4[i];
        *(float4*)&sY[i >> 2][(i & 3) * 4] = v;
    }
    __syncthreads();

    const double al = 1.0 / (1.0 + exp(-(double)alphas[f]));
    const double be = 1.0 / (1.0 + exp(-(double)betas[f]));
    const double ga = 1.0 / (1.0 + exp(-(double)gammas[f]));
    const double om = 1.0 / (1.0 + exp(-(double)omegas[f]));
    const double one_m_al = 1.0 - al, one_m_be = 1.0 - be;
    const double one_p_be = 1.0 + be;
    const double one_m_ga = 1.0 - ga, one_m_om = 1.0 - om;
    const double inv_al = nrcp(al);
    const double ga_al  = ga * inv_al;
    const double om_al  = om * inv_al;
    const double A_ = one_p_be * one_m_al + one_m_be;

    // ---------------- per-lane window coefficients ----------------
    double Pl = (j == 0) ? 1.0 : 0.0;
    double Ql = 0.0;
    {
        double p = 1.0, q = 0.0, pn = 0.0, qn = 1.0;
        #pragma unroll
        for (int it = 1; it <= 7; ++it) {
            double p2 = fma(A_, p, -pn);
            double q2 = fma(A_, q, -qn);
            pn = one_m_al * p; qn = one_m_al * q;
            p = p2; q = q2;
            if (j == it) { Pl = p; Ql = q; }
        }
    }
    double R_[8];
    R_[0] = one_p_be;
    {
        double r = one_p_be, rn = 1.0;
        #pragma unroll
        for (int m = 1; m < 8; ++m) {
            double r2 = fma(A_, r, -rn);
            rn = one_m_al * r;
            r = r2;
            R_[m] = r;
        }
    }
    double cf[8];
    #pragma unroll
    for (int i = 0; i < 8; ++i) cf[i] = 0.0;
    #pragma unroll
    for (int i = 0; i < 7; ++i) {
        #pragma unroll
        for (int m = 0; m + i + 1 <= 7; ++m) {
            if (j == i + m + 1) cf[i] = R_[m];
        }
    }

    // ---------------- init (lane-parallel sums + group reduce) -------------
    double pa = 0.0, pb = 0.0;
    #pragma unroll
    for (int m = 0; m < 21; ++m) {
        pa += (double)sY[j + 8 * m][s_loc];
        pb += (double)sY[j + 8 * m + P2c][s_loc];
    }
    pa += xor8<1>(pa); pb += xor8<1>(pb);
    pa += xor8<2>(pa); pb += xor8<2>(pb);
    pa += xor8<4>(pa); pb += xor8<4>(pb);
    const double sa = pa, sb = pb;

    double Icr_own[3];
    {
        double icv[3];
        double pc = 0.0;
        #pragma unroll
        for (int m2 = 0; m2 < 3; ++m2) {
            const int ph = j + 8 * m2;
            double v0 = (double)sY[ph][s_loc];
            double v1 = (double)sY[ph + P1c][s_loc];
            icv[m2] = 0.5 * (v0 + v1);
            pc += v0 + v1;
        }
        pc += xor8<1>(pc);
        pc += xor8<2>(pc);
        pc += xor8<4>(pc);
        const double inv_mean48 = 48.0 * nrcp(pc);
        #pragma unroll
        for (int m2 = 0; m2 < 3; ++m2) Icr_own[m2] = icv[m2] * inv_mean48;
    }

    const double mean336     = (sa + sb) * (1.0 / 336.0);
    const double inv_mean336 = nrcp(mean336);
    {
        double rI[3];
        #pragma unroll
        for (int m2 = 0; m2 < 3; ++m2)
            rI[m2] = inv_mean336 * nrcp(Icr_own[m2]);
        #pragma unroll
        for (int m = 0; m < 21; ++m) {
            const int row = j + 8 * m;
            double v0 = (double)sY[row][s_loc];
            double v1 = (double)sY[row + P2c][s_loc];
            sW[row][s_loc] = 0.5 * (v0 + v1) * rI[m % 3];
        }
    }

    double tt0 = 0.5 * ((sa - sb) * (1.0 / (168.0 * 168.0)) +
                        ((double)sY[P2c - 1][s_loc] - (double)sY[0][s_loc]) * (1.0 / 168.0));
    double ss0 = mean336 - 168.5 * tt0;

    double spt0 = ss0 + tt0;      // spt_0
    double snp0 = ss0;            // snew_{-1}

    // ---------------- pipelined windowed scan: 64 windows of 8 -------------
    double b0, b1, b2, b3, b4, b5, b6, b7;       // bcast aur, current window
    double n0, n1, n2, n3, n4, n5, n6, n7;       // bcast aur, next window
    double aurC, aurN, aurP;                     // own aur (cur/next/prev)
    double iwC, iwN;
    double wcC, wcN, wcP;
    double snwP = 0.0;
    int rowC, rowN, rowP, KbC, KbN;

    // PRE for window w: reads sW[rowN + j], sY[KbN + j], Ic phase SEL;
    // produces n0..n7, aurN, iwN, wcN.
#define PRE(SEL)                                                              \
    {                                                                         \
        wcN = sW[rowN + j][s_loc];                                            \
        double yvN = (double)sY[KbN + j][s_loc];                              \
        iwN = Icr_own[SEL] * wcN;                                             \
        double invN = nrcp1(iwN);                                             \
        aurN = (al * yvN) * invN;                                             \
        n0 = bcast8<0>(aurN); n1 = bcast8<1>(aurN);                           \
        n2 = bcast8<2>(aurN); n3 = bcast8<3>(aurN);                           \
        n4 = bcast8<4>(aurN); n5 = bcast8<5>(aurN);                           \
        n6 = bcast8<6>(aurN); n7 = bcast8<7>(aurN);                           \
    }
    // deferred D' of the previous window
#define DPR(PSEL)                                                             \
    {                                                                         \
        double x = aurP * __builtin_amdgcn_rcp(snwP);                         \
        Icr_own[PSEL] *= fma(ga_al, x, one_m_ga);                             \
        sW[rowP + j][s_loc] = wcP * fma(om_al, x, one_m_om);                  \
    }
    // serial phase of the current window (uses b*, aurC, iwC, KbC)
#define SER                                                                   \
    double snwS;                                                              \
    {                                                                         \
        double t0 = fma(cf[0], b0, cf[1] * b1);                               \
        double t1 = fma(cf[2], b2, cf[3] * b3);                               \
        double t2 = fma(cf[4], b4, cf[5] * b5);                               \
        double t3 = fma(cf[6], b6, cf[7] * b7);                               \
        double v  = (t0 + t1) + (t2 + t3);                                    \
        double acc = fma(Pl, spt0, fma(Ql, snp0, v));                         \
        snwS = fma(one_m_al, acc, aurC);                                      \
        sY[KbC + j][s_loc] = (float)(acc * iwC);                              \
        double accB7 = bcast8<7>(acc);                                        \
        double snwB7 = bcast8<7>(snwS);                                       \
        double snwB6 = bcast8<6>(snwS);                                       \
        spt0 = fma(one_p_be, snwB7, fma(one_m_be, accB7, -snwB6));            \
        snp0 = snwB7;                                                         \
    }
#define ROT                                                                   \
    {                                                                         \
        aurP = aurC; snwP = snwS; wcP = wcC; rowP = rowC;                     \
        aurC = aurN; iwC = iwN; wcC = wcN;                                    \
        b0 = n0; b1 = n1; b2 = n2; b3 = n3;                                   \
        b4 = n4; b5 = n5; b6 = n6; b7 = n7;                                   \
        rowC = rowN; rowN = (rowN + 8 == P2c) ? 0 : rowN + 8;                 \
        KbC = KbN; KbN += 8;                                                  \
    }

    // prologue: prefetch w0, shift into current slots
    rowN = 0; KbN = 0;
    PRE(0)
    b0 = n0; b1 = n1; b2 = n2; b3 = n3; b4 = n4; b5 = n5; b6 = n6; b7 = n7;
    aurC = aurN; iwC = iwN; wcC = wcN;
    rowC = 0; KbC = 0; rowP = 0; wcP = 0.0; aurP = 0.0;
    rowN = 8; KbN = 8;

    // k=0: w0 (no D')
    { PRE(1) SER ROT }
    // k=1, k=2
    { PRE(2) DPR(0) SER ROT }
    { PRE(0) DPR(1) SER ROT }
    // k=3..62: 20 x { (1,2), (2,0), (0,1) }
    #pragma unroll 1
    for (int it = 0; it < 20; ++it) {
        { PRE(1) DPR(2) SER ROT }
        { PRE(2) DPR(0) SER ROT }
        { PRE(0) DPR(1) SER ROT }
    }
    // k=63: no PRE
    { DPR(2) SER ROT }
    // final drain: D' of w63 (phase 63%3 = 0)
    DPR(0)

#undef PRE
#undef DPR
#undef SER
#undef ROT

    const double ss_f = snp0;           // snew_511
    const double tt_f = spt0 - snp0;    // tnew_511

    // ================ fused epilogue (all block-local) ================
    sIc[j     ][s_loc] = Icr_own[0];
    sIc[j + 8 ][s_loc] = Icr_own[1];
    sIc[j + 16][s_loc] = Icr_own[2];

    // Ic out, rolled +8: out[jj] = Ic[(jj+8)%24]  ->  jj = (p+16)%24
    {
        float* __restrict__ ic_o = out + OFF_IC + (size_t)bb * P1c * NFc + f;
        ic_o[((j + 16) % P1c) * NFc] = (float)Icr_own[0];   // p = j
        ic_o[( j            ) * NFc] = (float)Icr_own[1];   // p = j+8
        ic_o[((j + 8 ) % P1c) * NFc] = (float)Icr_own[2];   // p = j+16
    }
    if (j == 0) {
        out[OFF_T + bb * NFc + f] = (float)tt_f;
        out[OFF_S + bb * NFc + f] = (float)ss_f;
    }

    // yhat + e flush (coalesced float4; y re-read from global, L2-hot)
    __syncthreads();
    {
        float* __restrict__ yho = out + OFF_YH + (size_t)bb * NSTEP * NFc;
        float* __restrict__ eo  = out + OFF_E  + (size_t)bb * NSTEP * NFc;
        #pragma unroll 4
        for (int i = tid; i < (NSTEP * NFc) / 4; i += 128) {
            float4 yh4 = *(const float4*)&sY[i >> 2][(i & 3) * 4];
            float4 yv4 = y4[i];
            ((float4*)yho)[i] = yh4;
            float4 ev;
            ev.x = yv4.x - yh4.x; ev.y = yv4.y - yh4.y;
            ev.z = yv4.z - yh4.z; ev.w = yv4.w - yh4.w;
            ((float4*)eo)[i] = ev;
        }
    }
    __syncthreads();

    // fc stage into freed sY rows 0..335; wc (rolled +8) into rows 336..503
    {
        int p1i = j + 8;                 // (k+8) % 24, rolling
        int p2i = j + 8;                 // (k+8) % 168, rolling
        #pragma unroll 6
        for (int m = 0; m < 42; ++m) {
            const int k = j + 8 * m;
            double cb = sIc[p1i][s_loc];
            double cc = sW[p2i][s_loc];
            double ca = fma((double)(k + 1), tt_f, ss_f);
            sY[k][s_loc] = (float)(ca * cb * cc);
            p1i += 8; p1i = (p1i >= P1c) ? (p1i - P1c) : p1i;
            p2i += 8; p2i = (p2i >= P2c) ? (p2i - P2c) : p2i;
        }
        #pragma unroll
        for (int m = 0; m < 21; ++m) {
            const int row = j + 8 * m;
            const int jj  = (row >= 8) ? (row - 8) : (row + 160);
            sY[MAXH + jj][s_loc] = (float)sW[row][s_loc];
        }
    }
    __syncthreads();

    // fc + wc flush (coalesced float4)
    {
        float* __restrict__ fco = out + OFF_FC + (size_t)bb * MAXH * NFc;
        #pragma unroll 4
        for (int i = tid; i < (MAXH * NFc) / 4; i += 128) {
            ((float4*)fco)[i] = *(const float4*)&sY[i >> 2][(i & 3) * 4];
        }
        float* __restrict__ wco = out + OFF_WC + (size_t)bb * P2c * NFc;
        #pragma unroll 4
        for (int i = tid; i < (P2c * NFc) / 4; i += 128) {
            ((float4*)wco)[i] = *(const float4*)&sY[MAXH + (i >> 2)][(i & 3) * 4];
        }
    }
}

extern "C" void kernel_launch(void* const* d_in, const int* in_sizes, int n_in,
                              void* d_out, int out_size, void* d_ws, size_t ws_size,
                              hipStream_t stream)
{
    const float* y      = (const float*)d_in[0];
    const float* alphas = (const float*)d_in[1];
    const float* betas  = (const float*)d_in[2];
    const float* gammas = (const float*)d_in[3];
    const float* omegas = (const float*)d_in[4];
    float* out = (float*)d_out;

    hipLaunchKernelGGL(dshw_one, dim3(BSc), dim3(128), 0, stream,
                       y, alphas, betas, gammas, omegas, out);
}